// Round 13
// baseline (718.783 us; speedup 1.0000x reference)
//
#include <hip/hip_runtime.h>
#include <stdint.h>

// DynamicQuantizedLinear on MI355X.
// R11 lessons: (a) fused in-loop B-dequant exposed HBM latency at each barrier
// (GEMM 256->364us) -> reverted to split prep_w; (b) ~195us of total is fixed
// harness overhead (restore/poison) -> only GEMM optimization pays.
// This round: counted-vmcnt deep pipeline (T4) in the race-free 3-slot form:
// compute K-tile kt from slot kt%3 while DMA-staging kt+2 into slot (kt+2)%3
// (never read during kt/kt+1 -> no write/read race by construction).
// Per-wave s_waitcnt vmcnt(2) BEFORE the boundary s_barrier (wait-then-barrier
// => all waves' DMA portions visible), raw s_barrier (no vmcnt drain!),
// 2 phases/K-tile with setprio(1) around MFMA (T5), sched_barrier(0) fences.

#define M_DIM 2048
#define N_DIM 11008
#define K_DIM 4096
#define BM 128
#define BN 128
#define BK 64
#define NKT (K_DIM / BK)          // 64

#define NWQ (N_DIM * K_DIM / 4)   // W quads: 11,272,192 = 44032 * 256
#define NXQ (M_DIM * K_DIM / 4)   // x quads:  2,097,152 =  8192 * 256

typedef _Float16 f16x4 __attribute__((ext_vector_type(4)));
typedef _Float16 f16x8 __attribute__((ext_vector_type(8)));
typedef float    f32x4 __attribute__((ext_vector_type(4)));

// ---------------- pass 1a: dequantize W to fp16 (pure streaming) ----------------
__global__ __launch_bounds__(256)
void prep_w(const int* __restrict__ WQ, const float* __restrict__ SC,
            _Float16* __restrict__ W16)
{
  const int i = blockIdx.x * 256 + threadIdx.x;   // quad index, exact grid
  const int4 w = ((const int4*)WQ)[i];            // 16B coalesced
  const float s = SC[i >> 10];                    // 1024 quads per K-row
  f16x4 o = { (_Float16)(w.x * s), (_Float16)(w.y * s),
              (_Float16)(w.z * s), (_Float16)(w.w * s) };
  ((f16x4*)W16)[i] = o;                           // 8B coalesced
}

// ---------------- pass 1b: downcast x to fp16 ----------------
__global__ __launch_bounds__(256)
void prep_x(const float* __restrict__ X, _Float16* __restrict__ X16)
{
  const int i = blockIdx.x * 256 + threadIdx.x;
  const float4 v = ((const float4*)X)[i];
  f16x4 o = { (_Float16)v.x, (_Float16)v.y, (_Float16)v.z, (_Float16)v.w };
  ((f16x4*)X16)[i] = o;
}

// ---------------- pass 2: f16 GEMM, 3-slot counted-vmcnt pipeline ----------------
// async global->LDS, 16B per lane. LDS dest = wave-uniform base + lane*16.
__device__ __forceinline__ void async_cp16(void* lds, const void* g) {
  auto l = (__attribute__((address_space(3))) uint32_t*)(uintptr_t)lds;
  auto p = (const __attribute__((address_space(1))) uint32_t*)(uintptr_t)g;
  __builtin_amdgcn_global_load_lds(p, l, 16, 0, 0);
}

__global__ __launch_bounds__(1024, 4)
void qlinear_gemm(const _Float16* __restrict__ A, const _Float16* __restrict__ B,
                  const float* __restrict__ BI, float* __restrict__ O)
{
  // 3 slots x (A[128][64] + B[128][64]) f16 = 3 x 32 KiB = 96 KiB
  __shared__ __align__(16) _Float16 sA[3][BM * BK];
  __shared__ __align__(16) _Float16 sB[3][BN * BK];

  const int t    = threadIdx.x;        // 0..1023 (16 waves)
  const int lane = t & 63;
  const int wid  = t >> 6;             // 0..15
  const int wr   = wid >> 2;           // 0..3: 32 M-rows each
  const int wc   = wid & 3;            // 0..3: 32 N-cols each
  const int fr   = lane & 15;          // A/B fragment row; C col
  const int fq   = lane >> 4;          // k-group (0..3)

  // Grid swizzle (verbatim from R9, measured FETCH 1.01GB->342MB):
  // XCD-chunked (1376 = 8*172) then bm-fastest (16 blocks share one W panel).
  const int wg = (blockIdx.x & 7) * 172 + (blockIdx.x >> 3);
  const int m0 = (wg & 15) * BM;
  const int n0 = (wg >> 4) * BN;

  // Staging: one K-tile = 128 rows x 64 cols f16 = 16 KiB = 1024 x 16B chunks
  // = exactly ONE global_load_lds call by 1024 lanes. chunk c = t:
  // row = t>>3, col8 = t&7. LDS linear in chunk order == row-major [128][64].
  const _Float16* gA0 = A + (size_t)(m0 + (t >> 3)) * K_DIM + (t & 7) * 8;
  const _Float16* gB0 = B + (size_t)(n0 + (t >> 3)) * K_DIM + (t & 7) * 8;
  const int wchunk = t & ~63;                 // wave-uniform chunk base
  _Float16* lA = &sA[0][0] + wchunk * 8;      // chunk*16B = chunk*8 f16
  _Float16* lB = &sB[0][0] + wchunk * 8;

  f32x4 acc[2][2] = {};                       // per-wave 32x32 output

#define STAGE(slot, kt) do {                                       \
    async_cp16((void*)(lA + (slot) * (BM * BK)), gA0 + (kt) * BK); \
    async_cp16((void*)(lB + (slot) * (BN * BK)), gB0 + (kt) * BK); \
  } while (0)

  // prologue: stage kt0 -> slot0, kt1 -> slot1 (4 calls in flight)
  STAGE(0, 0);
  STAGE(1, 1);

  int s = 0;                                  // kt % 3
  for (int kt = 0; kt < NKT; ++kt) {
    const int s2 = (s + 2 >= 3) ? s - 1 : s + 2;   // (kt+2) % 3

    // -- K-tile boundary: per-wave counted wait, THEN barrier --------------
    // Each wave waits for ITS OWN 2 calls of kt (issued at kt-2 / prologue),
    // leaving kt+1's 2 calls in flight. The barrier then guarantees every
    // wave's DMA portion of slot s has landed before anyone reads it.
    if (kt < NKT - 1) asm volatile("s_waitcnt vmcnt(2)" ::: "memory");
    else              asm volatile("s_waitcnt vmcnt(0)" ::: "memory");
    __builtin_amdgcn_s_barrier();             // raw barrier: NO vmcnt drain
    __builtin_amdgcn_sched_barrier(0);

    const _Float16* aP = &sA[s][0] + (wr * 32 + fr) * BK + fq * 8;
    const _Float16* bP = &sB[s][0] + (wc * 32 + fr) * BK + fq * 8;

    // -- phase 0: stage kt+2, read B-frags + A-frags(mf=0), 4 MFMA ---------
    if (kt + 2 < NKT) STAGE(s2, kt + 2);      // into slot never read in kt/kt+1

    f16x8 bf[2][2], af0[2];
#pragma unroll
    for (int nf = 0; nf < 2; ++nf)
#pragma unroll
      for (int kk = 0; kk < 2; ++kk)
        bf[nf][kk] = *(const f16x8*)(bP + nf * 16 * BK + kk * 32);
#pragma unroll
    for (int kk = 0; kk < 2; ++kk)
      af0[kk] = *(const f16x8*)(aP + kk * 32);

    __builtin_amdgcn_s_setprio(1);
#pragma unroll
    for (int kk = 0; kk < 2; ++kk)
#pragma unroll
      for (int nf = 0; nf < 2; ++nf)
        acc[0][nf] = __builtin_amdgcn_mfma_f32_16x16x32_f16(af0[kk], bf[nf][kk], acc[0][nf], 0, 0, 0);
    __builtin_amdgcn_s_setprio(0);

    __builtin_amdgcn_s_barrier();             // lockstep (raw)
    __builtin_amdgcn_sched_barrier(0);

    // -- phase 1: read A-frags(mf=1), 4 MFMA -------------------------------
    f16x8 af1[2];
#pragma unroll
    for (int kk = 0; kk < 2; ++kk)
      af1[kk] = *(const f16x8*)(aP + 16 * BK + kk * 32);

    __builtin_amdgcn_s_setprio(1);
#pragma unroll
    for (int kk = 0; kk < 2; ++kk)
#pragma unroll
      for (int nf = 0; nf < 2; ++nf)
        acc[1][nf] = __builtin_amdgcn_mfma_f32_16x16x32_f16(af1[kk], bf[nf][kk], acc[1][nf], 0, 0, 0);
    __builtin_amdgcn_s_setprio(0);

    s = (s + 1 == 3) ? 0 : s + 1;
    // next iteration's vmcnt-wait + barrier closes this K-tile
  }

  // epilogue: C/D layout col=lane&15, row=(lane>>4)*4+j. Scale folded in W16.
  // Reference rounding order: fp16(dot), then +bias in fp16, store f32.
  const int om = m0 + wr * 32;
  const int on = n0 + wc * 32;
#pragma unroll
  for (int nf = 0; nf < 2; ++nf) {
    const int n = on + nf * 16 + fr;
    const float b = BI[n];
#pragma unroll
    for (int mf = 0; mf < 2; ++mf) {
      const int m = om + mf * 16 + fq * 4;
#pragma unroll
      for (int j = 0; j < 4; ++j) {
        const _Float16 h = (_Float16)acc[mf][nf][j];
        const _Float16 r = (_Float16)((float)h + b);
        O[(size_t)(m + j) * N_DIM + n] = (float)r;
      }
    }
  }
#undef STAGE
}

extern "C" void kernel_launch(void* const* d_in, const int* in_sizes, int n_in,
                              void* d_out, int out_size, void* d_ws, size_t ws_size,
                              hipStream_t stream) {
  const float* x  = (const float*)d_in[0];
  const int*   wq = (const int*)d_in[1];
  const float* sc = (const float*)d_in[2];
  const float* bi = (const float*)d_in[3];
  float* out = (float*)d_out;

  _Float16* x16 = (_Float16*)d_ws;                                      // 16 MB
  _Float16* w16 = (_Float16*)((char*)d_ws + (size_t)M_DIM * K_DIM * 2); // 90 MB
  const size_t need = (size_t)M_DIM * K_DIM * 2 + (size_t)N_DIM * K_DIM * 2;
  if (ws_size < need) return;  // leave output poisoned (clear signal)

  prep_w<<<dim3(NWQ / 256), dim3(256), 0, stream>>>(wq, sc, w16);   // ~61 us
  prep_x<<<dim3(NXQ / 256), dim3(256), 0, stream>>>(x, x16);        // ~13 us

  dim3 grid((M_DIM / BM) * (N_DIM / BN));   // 16 * 86 = 1376 blocks
  qlinear_gemm<<<grid, dim3(1024), 0, stream>>>(x16, w16, bi, out);
}